// Round 9
// baseline (206.470 us; speedup 1.0000x reference)
//
#include <hip/hip_runtime.h>
#include <cstdint>

typedef __bf16 bf16;
typedef __bf16 bf16x8 __attribute__((ext_vector_type(8)));
typedef __bf16 bf16x4 __attribute__((ext_vector_type(4)));
typedef float  f32x4  __attribute__((ext_vector_type(4)));

#define MFMA_BF16(a, b, c) __builtin_amdgcn_mfma_f32_16x16x32_bf16(a, b, c, 0, 0, 0)

#define WAITCNT_VM(n) asm volatile("s_waitcnt vmcnt(" #n ")" ::: "memory")
#define CFENCE()      asm volatile("" ::: "memory")

// async global->LDS, 16B/lane; LDS dest affine in lane (base + lane*16).
__device__ __forceinline__ void async_load16(const void* g, void* l) {
    __builtin_amdgcn_global_load_lds(
        (__attribute__((address_space(1))) uint32_t*)(uintptr_t)g,
        (__attribute__((address_space(3))) uint32_t*)(uint32_t)(uintptr_t)l,
        16, 0, 0);
}

// ---------------- fused fp32 -> bf16 convert (x + w_qkv in one launch) ----------------
__global__ void cvt3_kernel(const float* __restrict__ s0, bf16* __restrict__ d0, int n0,
                            const float* __restrict__ s1, bf16* __restrict__ d1, int n1) {
    int i = blockIdx.x * blockDim.x + threadIdx.x;
    const float* s; bf16* d; int j = i;
    if (j < n0) { s = s0; d = d0; }
    else { j -= n0; if (j >= n1) return; s = s1; d = d1; }
    float4 v = ((const float4*)s)[j];
    bf16x4 o;
    o[0] = (bf16)v.x; o[1] = (bf16)v.y; o[2] = (bf16)v.z; o[3] = (bf16)v.w;
    ((bf16x4*)d)[j] = o;
}

// ---------------- QKV GEMM: 128x64 tile (1536 blocks = 4/CU), 3-deep 2-barrier + T2 + T1 ----------------
// R9: R8's 1-barrier rotation reverted (regressed). Grid was the TLP cap: 768 blocks =
// exactly 3/CU. Halving BN to 64 -> 1536 blocks, 4 blocks/CU (36KB LDS), 16 waves/CU.
// Wave grid 2x2, wave tile 64x32 (8 MFMA/iter). Staging 3 loads/thread (A rows r,r+64;
// B row r), source-swizzled with key (row>>1)&3 (preserved under +64). vmcnt 6/3/0.
__global__ __launch_bounds__(256) void gemm_qkv_kernel(
    const bf16* __restrict__ A, const bf16* __restrict__ W,
    const float* __restrict__ bias,
    bf16* __restrict__ Qb, bf16* __restrict__ Kb, bf16* __restrict__ Vt)
{
    const int Kd = 1024;
    __shared__ __attribute__((aligned(16))) bf16 smem[3 * 6144];   // 36KB: sA[3](8KB) | sB[3](4KB)
    bf16* const sA0 = smem;                // 3 x 4096 elems
    bf16* const sB0 = smem + 3 * 4096;     // 3 x 2048 elems
    int tid = threadIdx.x, lane = tid & 63, wid = tid >> 6;
    int flat = blockIdx.y * 48 + blockIdx.x;          // 0..1535
    int orig = (flat & 7) * 192 + (flat >> 3);        // XCD-contiguous (1536 % 8 == 0)
    int m0 = (orig / 48) * 128, n0 = (orig % 48) * 64;
    int ra = tid >> 2;                            // 0..63 (A rows ra, ra+64; B row ra)
    int ca = tid & 3;                             // physical chunk (LDS dest, linear)
    int jca = ca ^ ((ra >> 1) & 3);               // logical chunk (global source)
    const bf16* Ag = A + (size_t)(m0 + ra) * Kd + jca * 8;
    const bf16* Wg = W + (size_t)(n0 + ra) * Kd + jca * 8;
    int aoff = ra * 32 + ca * 8;
    int wm = (wid & 1) * 64, wn = (wid >> 1) * 32;
    int lcol = lane & 15, quad = lane >> 4;
    int ckey = (lcol >> 1) & 3;                   // read-side swizzle key
    f32x4 acc[4][2] = {};
#define STG_Q(buf, k0_) do { \
        async_load16(Ag + (k0_), sA0 + (buf) * 4096 + aoff); \
        async_load16(Ag + (k0_) + 64 * Kd, sA0 + (buf) * 4096 + aoff + 2048); \
        async_load16(Wg + (k0_), sB0 + (buf) * 2048 + aoff); \
    } while (0)
    STG_Q(0, 0);
    STG_Q(1, 32);
    STG_Q(2, 64);
    int cur = 0;
    for (int it = 0; it < 32; ++it) {
        if (it < 30)      { WAITCNT_VM(6); }   // tiles it+1, it+2 stay in flight
        else if (it == 30){ WAITCNT_VM(3); }
        else              { WAITCNT_VM(0); }
        __builtin_amdgcn_s_barrier();   // buf[cur] staged by ALL waves
        CFENCE();
        const bf16* cA = sA0 + cur * 4096;
        const bf16* cB = sB0 + cur * 2048;
        bf16x8 af[4], bfr[2];
#pragma unroll
        for (int i = 0; i < 4; i++)
            af[i] = *(const bf16x8*)&cA[(wm + i * 16 + lcol) * 32 + (quad ^ ckey) * 8];
#pragma unroll
        for (int j = 0; j < 2; j++)
            bfr[j] = *(const bf16x8*)&cB[(wn + j * 16 + lcol) * 32 + (quad ^ ckey) * 8];
#pragma unroll
        for (int i = 0; i < 4; i++)
#pragma unroll
            for (int j = 0; j < 2; j++)
                acc[i][j] = MFMA_BF16(af[i], bfr[j], acc[i][j]);
        CFENCE();
        __builtin_amdgcn_s_barrier();   // all waves done reading buf[cur]
        if (it + 3 < 32) STG_Q(cur, (it + 3) * 32);   // refill the buffer just consumed
        cur = (cur == 2) ? 0 : cur + 1;
    }
#undef STG_Q
    // ---- coalesced epilogue (LDS restage; whole block is one head-column of Q/K/V) ----
    int part = n0 >> 10;
    int h0 = (n0 & 1023) >> 6;
    int b = m0 >> 10, s0 = m0 & 1023;
    bf16* sE = smem;
    if (part == 2) {
        const int LP = 136;                    // [n][m] layout, 64 x 128 (pad 8)
#pragma unroll
        for (int j = 0; j < 2; j++) {
            float bv = bias[n0 + wn + j * 16 + lcol];
#pragma unroll
            for (int i = 0; i < 4; i++)
#pragma unroll
                for (int r = 0; r < 4; r++)
                    sE[(wn + j * 16 + lcol) * LP + (wm + i * 16 + quad * 4 + r)] = (bf16)(acc[i][j][r] + bv);
        }
        __syncthreads();
#pragma unroll
        for (int p = 0; p < 4; p++) {
            int c = p * 256 + tid;
            int nl = c >> 4, mc = (c & 15) * 8;   // 64 rows x 128 cols
            *(bf16x8*)&Vt[(size_t)((b * 16 + h0) * 64 + nl) * 1024 + s0 + mc] = *(const bf16x8*)&sE[nl * LP + mc];
        }
    } else {
        const int LP = 72;                     // [m][n] layout, 128 x 64 (pad 8)
        float scv = (part == 0) ? 0.125f : 1.0f;
        bf16* dst = (part == 0) ? Qb : Kb;
#pragma unroll
        for (int j = 0; j < 2; j++) {
            float bv = bias[n0 + wn + j * 16 + lcol];
#pragma unroll
            for (int i = 0; i < 4; i++)
#pragma unroll
                for (int r = 0; r < 4; r++)
                    sE[(wm + i * 16 + quad * 4 + r) * LP + (wn + j * 16 + lcol)] = (bf16)((acc[i][j][r] + bv) * scv);
        }
        __syncthreads();
#pragma unroll
        for (int p = 0; p < 4; p++) {
            int c = p * 256 + tid;
            int m = c >> 3, nc = (c & 7) * 8;     // 128 rows x 64 cols
            *(bf16x8*)&dst[(size_t)((b * 16 + h0) * 1024 + s0 + m) * 64 + nc] = *(const bf16x8*)&sE[m * LP + nc];
        }
    }
}

// ---------------- flash attention (+ piggybacked w_out cvt): 8-wave blocks ----------------
__global__ __launch_bounds__(512) void flash_kernel(
    const bf16* __restrict__ Qb, const bf16* __restrict__ Kb, const bf16* __restrict__ Vt,
    bf16* __restrict__ ctx, float* __restrict__ ml,
    const float* __restrict__ wof, bf16* __restrict__ wob)
{
    __shared__ bf16 sK[2][64 * 64];     // [buf][key][d], chunk-swizzled
    __shared__ bf16 sV[2][64 * 64];     // [buf][d][key], chunk-swizzled
    __shared__ bf16 pt[8][16 * 64];     // per-wave 16q x 64k transpose tile, XOR-swizzled
    int tid = threadIdx.x, lane = tid & 63, wid = tid >> 6;
    int bx = blockIdx.x;
    if (bx >= 512) {
        int i = (bx - 512) * 512 + tid;          // [0, 262144)
        float4 v = ((const float4*)wof)[i];
        bf16x4 o;
        o[0] = (bf16)v.x; o[1] = (bf16)v.y; o[2] = (bf16)v.z; o[3] = (bf16)v.w;
        ((bf16x4*)wob)[i] = o;
        return;
    }
    int orig = (bx & 7) * 64 + (bx >> 3);   // XCD-contiguous remap (bijective over 512)
    int qt = orig & 7;
    int h = (orig >> 3) & 15;
    int b = orig >> 7;
    int lcol = lane & 15, quad = lane >> 4;
    size_t base = (size_t)(b * 16 + h) * 65536;

    int q0 = qt * 128 + wid * 16;
    const bf16* qp = Qb + base + (size_t)(q0 + lcol) * 64 + quad * 8;
    bf16x8 a0 = *(const bf16x8*)qp;
    bf16x8 a1 = *(const bf16x8*)(qp + 32);

    char* wpt = (char*)&pt[wid][0];
    int sr = tid >> 3;                   // staged row 0..63
    int pp = tid & 7;                    // physical chunk
    int jj = pp ^ (sr & 7);              // logical chunk (swizzle key = row & 7)
    int sw = lcol & 7;                   // read-side swizzle key

#define STAGE_KV(buf, kt_) do { \
        async_load16(Kb + base + (size_t)((kt_) * 64 + sr) * 64 + jj * 8, &sK[buf][sr * 64 + pp * 8]); \
        async_load16(Vt + base + (size_t)sr * 1024 + (kt_) * 64 + jj * 8, &sV[buf][sr * 64 + pp * 8]); \
    } while (0)

    float l_[4] = {0.f, 0.f, 0.f, 0.f};
    f32x4 o[4] = {};

    STAGE_KV(0, 0);
    int cur = 0;
    for (int kt = 0; kt < 16; kt++) {
        __syncthreads();
        if (kt < 15) STAGE_KV(cur ^ 1, kt + 1);
        const bf16* sKc = &sK[cur][0];
        const bf16* sVc = &sV[cur][0];
#pragma unroll
        for (int nt = 0; nt < 4; nt++) {
            int ck = quad ^ sw;
            bf16x8 bk0 = *(const bf16x8*)&sKc[(nt * 16 + lcol) * 64 + ck * 8];
            bf16x8 bk1 = *(const bf16x8*)&sKc[(nt * 16 + lcol) * 64 + (ck ^ 4) * 8];
            f32x4 s = {};
            s = MFMA_BF16(a0, bk0, s);
            s = MFMA_BF16(a1, bk1, s);
#pragma unroll
            for (int rr = 0; rr < 4; rr++) {
                float p = __expf(s[rr]);
                l_[rr] += p;
                int row = quad * 4 + rr;
                *(bf16*)(wpt + row * 128 + ((nt * 32 + lcol * 2) ^ ((row & 7) << 4))) = (bf16)p;
            }
        }
#pragma unroll
        for (int kf = 0; kf < 2; kf++) {
            bf16x8 pa = *(const bf16x8*)(wpt + lcol * 128 + (((kf * 4 + quad) ^ sw) << 4));
#pragma unroll
            for (int dt = 0; dt < 4; dt++) {
                bf16x8 vb = *(const bf16x8*)&sVc[(dt * 16 + lcol) * 64 + ((kf * 4 + quad) ^ sw) * 8];
                o[dt] = MFMA_BF16(pa, vb, o[dt]);
            }
        }
        cur ^= 1;
    }
#undef STAGE_KV
#pragma unroll
    for (int mk = 1; mk < 16; mk <<= 1)
#pragma unroll
        for (int rr = 0; rr < 4; rr++) l_[rr] += __shfl_xor(l_[rr], mk, 64);
    // stage o -> pt (wave-private, swizzled), then coalesced 16B stores
#pragma unroll
    for (int rr = 0; rr < 4; rr++) {
        float inv = 1.f / l_[rr];
        int row = quad * 4 + rr;
#pragma unroll
        for (int dt = 0; dt < 4; dt++)
            *(bf16*)(wpt + row * 128 + ((dt * 32 + lcol * 2) ^ ((row & 7) << 4))) = (bf16)(o[dt][rr] * inv);
        if (lcol == 0)
            ml[(size_t)(b * 16 + h) * 1024 + q0 + row] = l_[rr];
    }
    int r8a = lane >> 3, ca = lane & 7;
#pragma unroll
    for (int half = 0; half < 2; half++) {
        int r8 = r8a + half * 8;
        bf16x8 v = *(const bf16x8*)(wpt + r8 * 128 + ((ca * 16) ^ ((r8 & 7) << 4)));
        *(bf16x8*)&ctx[(size_t)(b * 1024 + q0 + r8) * 1024 + h * 64 + ca * 8] = v;
    }
}

// ---------------- MERGED aw + out-proj GEMM (independent ops, one launch = overlap) ----------------
// Blocks 0..511: aw (8-wave, reg-pipelined Q/ml). Blocks 512..767: out-proj 128x128-tile
// GEMM (8-wave, R7's 3-deep 2-barrier counted-vmcnt schedule). ao -> y_out scratch.
__global__ __launch_bounds__(512) void awo_kernel(
    const bf16* __restrict__ Qb, const bf16* __restrict__ Kb,
    const float* __restrict__ ml, float* __restrict__ aw,
    const bf16* __restrict__ ctx, const bf16* __restrict__ wob,
    const float* __restrict__ bias, float* __restrict__ yao)
{
    __shared__ __attribute__((aligned(16))) bf16 smem[6 * 128 * 32];   // 48KB union
    int tid = threadIdx.x, lane = tid & 63, wid = tid >> 6;
    int bx = blockIdx.x;
    int lcol = lane & 15, quad = lane >> 4;

    if (bx >= 512) {
        // ---- out-proj GEMM: 128x128 tile, 512 threads, 3-deep 2-barrier counted vmcnt ----
        const int Kd = 1024;
        bf16* const sA0 = smem;
        bf16* const sB0 = smem + 3 * 4096;
        int obx = bx - 512;                       // 0..255
        int m0 = (obx >> 3) * 128, n0 = (obx & 7) * 128;
        int srow = tid >> 2;                      // 0..127 (one 128x32 tile per stage)
        int pchunk = tid & 3;
        int jchunk = pchunk ^ ((tid >> 3) & 3);   // key=(srow>>1)&3
        const bf16* Ag = ctx + (size_t)(m0 + srow) * Kd + jchunk * 8;
        const bf16* Wg = wob + (size_t)(n0 + srow) * Kd + jchunk * 8;
        int soff = srow * 32 + pchunk * 8;
        int wm = (wid & 3) * 32, wn = (wid >> 2) * 64;
        int ckey = (lcol >> 1) & 3;
        f32x4 acc[2][4] = {};
#define STG_O(buf, k0_) do { \
        async_load16(Ag + (k0_), sA0 + (buf) * 4096 + soff); \
        async_load16(Wg + (k0_), sB0 + (buf) * 4096 + soff); \
    } while (0)
        STG_O(0, 0);
        STG_O(1, 32);
        STG_O(2, 64);
        int cur = 0;
        for (int it = 0; it < 32; ++it) {
            if (it < 30)      { WAITCNT_VM(4); }
            else if (it == 30){ WAITCNT_VM(2); }
            else              { WAITCNT_VM(0); }
            __builtin_amdgcn_s_barrier();
            CFENCE();
            const bf16* cA = sA0 + cur * 4096;
            const bf16* cB = sB0 + cur * 4096;
            bf16x8 af[2], bfr[4];
#pragma unroll
            for (int i = 0; i < 2; i++)
                af[i] = *(const bf16x8*)&cA[(wm + i * 16 + lcol) * 32 + (quad ^ ckey) * 8];
#pragma unroll
            for (int j = 0; j < 4; j++)
                bfr[j] = *(const bf16x8*)&cB[(wn + j * 16 + lcol) * 32 + (quad ^ ckey) * 8];
#pragma unroll
            for (int i = 0; i < 2; i++)
#pragma unroll
                for (int j = 0; j < 4; j++)
                    acc[i][j] = MFMA_BF16(af[i], bfr[j], acc[i][j]);
            CFENCE();
            __builtin_amdgcn_s_barrier();
            if (it + 3 < 32) STG_O(cur, (it + 3) * 32);
            cur = (cur == 2) ? 0 : cur + 1;
        }
#undef STG_O
#pragma unroll
        for (int j = 0; j < 4; j++) {
            int n = n0 + wn + j * 16 + lcol;
            float bv = bias[n];
#pragma unroll
            for (int i = 0; i < 2; i++) {
                int m = m0 + wm + i * 16 + quad * 4;
#pragma unroll
                for (int r = 0; r < 4; r++) yao[(size_t)(m + r) * 1024 + n] = acc[i][j][r] + bv;
            }
        }
        return;
    }

    // ---- aw: 8-wave, dbuf K staging, reg-pipelined Q/ml ----
    bf16* const sK0 = smem;                       // 2 x 4096 elements
    int orig = (bx & 7) * 64 + (bx >> 3);         // bijective over 512
    int kt = orig & 15;
    int qt = (orig >> 4) & 7;
    int b = orig >> 7;
    int q0 = qt * 128 + wid * 16;
    int kbase = kt * 64;
    int sw = lcol & 7;
    int sr = tid >> 3, pp = tid & 7, jj = pp ^ (sr & 7);   // 1 chunk per thread (8KB)

#define STAGE_K(buf, hh) \
        async_load16(Kb + (size_t)(b * 16 + (hh)) * 65536 + (size_t)(kbase + sr) * 64 + jj * 8, \
                     sK0 + (buf) * 4096 + sr * 64 + pp * 8)

    float acc[16];
#pragma unroll
    for (int i = 0; i < 16; i++) acc[i] = 0.f;

    bf16x8 a0c, a1c, a0n, a1n;
    float4 mvC, mvN;
    {
        const bf16* qp = Qb + (size_t)(b * 16) * 65536 + (size_t)(q0 + lcol) * 64 + quad * 8;
        a0c = *(const bf16x8*)qp;
        a1c = *(const bf16x8*)(qp + 32);
        mvC = *(const float4*)(ml + (size_t)(b * 16) * 1024 + q0 + quad * 4);
    }
    STAGE_K(0, 0);
    int cur = 0;
    for (int h = 0; h < 16; h++) {
        __syncthreads();
        if (h < 15) {
            STAGE_K(cur ^ 1, h + 1);
            const bf16* qp = Qb + (size_t)(b * 16 + h + 1) * 65536 + (size_t)(q0 + lcol) * 64 + quad * 8;
            a0n = *(const bf16x8*)qp;
            a1n = *(const bf16x8*)(qp + 32);
            mvN = *(const float4*)(ml + (size_t)(b * 16 + h + 1) * 1024 + q0 + quad * 4);
        }
        float scale[4] = {0.0625f / mvC.x, 0.0625f / mvC.y, 0.0625f / mvC.z, 0.0625f / mvC.w};
        const bf16* sKc = sK0 + cur * 4096;
#pragma unroll
        for (int nt = 0; nt < 4; nt++) {
            int ck = quad ^ sw;
            bf16x8 bk0 = *(const bf16x8*)&sKc[(nt * 16 + lcol) * 64 + ck * 8];
            bf16x8 bk1 = *(const bf16x8*)&sKc[(nt * 16 + lcol) * 64 + (ck ^ 4) * 8];
            f32x4 s = {};
            s = MFMA_BF16(a0c, bk0, s);
            s = MFMA_BF16(a1c, bk1, s);
#pragma unroll
            for (int rr = 0; rr < 4; rr++)
                acc[nt * 4 + rr] += __expf(s[rr]) * scale[rr];
        }
        if (h < 15) { a0c = a0n; a1c = a1n; mvC = mvN; }
        cur ^= 1;
    }
#undef STAGE_K
#pragma unroll
    for (int nt = 0; nt < 4; nt++)
#pragma unroll
        for (int rr = 0; rr < 4; rr++)
            aw[(size_t)(b * 1024 + q0 + quad * 4 + rr) * 1024 + kbase + nt * 16 + lcol] = acc[nt * 4 + rr];
}

// ---------------- residual + LayerNorm (in-place over yao = y_out) ----------------
__global__ __launch_bounds__(256) void ln_kernel(
    const float* __restrict__ x, const float* __restrict__ ao,
    const float* __restrict__ w, const float* __restrict__ bsh,
    float* __restrict__ y)
{
    int row = blockIdx.x, tid = threadIdx.x;
    float4 xv = ((const float4*)(x + (size_t)row * 1024))[tid];
    float4 av = ((const float4*)(ao + (size_t)row * 1024))[tid];
    float4 v = {xv.x + av.x, xv.y + av.y, xv.z + av.z, xv.w + av.w};
    float s = v.x + v.y + v.z + v.w;
    float ss = v.x * v.x + v.y * v.y + v.z * v.z + v.w * v.w;
#pragma unroll
    for (int off = 32; off; off >>= 1) { s += __shfl_down(s, off); ss += __shfl_down(ss, off); }
    __shared__ float rs[4], rss[4];
    int lane = tid & 63, wid = tid >> 6;
    if (lane == 0) { rs[wid] = s; rss[wid] = ss; }
    __syncthreads();
    s = rs[0] + rs[1] + rs[2] + rs[3];
    ss = rss[0] + rss[1] + rss[2] + rss[3];
    float mean = s * (1.f / 1024.f);
    float var = ss * (1.f / 1024.f) - mean * mean;
    float inv = rsqrtf(var + 1e-5f);
    float4 wv = ((const float4*)w)[tid];
    float4 bv = ((const float4*)bsh)[tid];
    float4 o;
    o.x = (v.x - mean) * inv * wv.x + bv.x;
    o.y = (v.y - mean) * inv * wv.y + bv.y;
    o.z = (v.z - mean) * inv * wv.z + bv.z;
    o.w = (v.w - mean) * inv * wv.w + bv.w;
    ((float4*)y)[row * 256 + tid] = o;
}

extern "C" void kernel_launch(void* const* d_in, const int* in_sizes, int n_in,
                              void* d_out, int out_size, void* d_ws, size_t ws_size,
                              hipStream_t stream) {
    const float* x     = (const float*)d_in[0];
    const float* w_qkv = (const float*)d_in[1];
    const float* b_qkv = (const float*)d_in[2];
    const float* w_out = (const float*)d_in[3];
    const float* b_out = (const float*)d_in[4];
    const float* ln_w  = (const float*)d_in[5];
    const float* ln_b  = (const float*)d_in[6];

    char* ws = (char*)d_ws;
    // [0,8M) Qb | [8,16M) Kb | [16,24M) Vt | [24,32M) ctx | [32,32.25M) ml |
    // x_bf [33,41M), wq_bf [41,47M) live only until gemm_qkv;
    // wo_bf [33,35M) after qkv (x_bf dead; written by flash-launch cvt riders);
    // ao lives in y_out (d_out scratch; ln runs in-place).
    bf16*   Qb    = (bf16*)(ws);
    bf16*   Kb    = (bf16*)(ws + (8ull  << 20));
    bf16*   Vt    = (bf16*)(ws + (16ull << 20));
    bf16*   ctx   = (bf16*)(ws + (24ull << 20));
    float*  ml    = (float*)(ws + (32ull << 20));
    bf16*   x_bf  = (bf16*)(ws + (33ull << 20));
    bf16*   wq_bf = (bf16*)(ws + (41ull << 20));
    bf16*   wo_bf = (bf16*)(ws + (33ull << 20));

    float* y_out  = (float*)d_out;
    float* aw_out = y_out + 4ull * 1024 * 1024;
    float* ao     = y_out;                      // scratch; ln in-place

    cvt3_kernel<<<7168, 256, 0, stream>>>(x, x_bf, 1048576, w_qkv, wq_bf, 786432);
    gemm_qkv_kernel<<<dim3(48, 32), 256, 0, stream>>>(x_bf, wq_bf, b_qkv, Qb, Kb, Vt);
    flash_kernel<<<1024, 512, 0, stream>>>(Qb, Kb, Vt, ctx, ml, w_out, wo_bf);
    awo_kernel<<<768, 512, 0, stream>>>(Qb, Kb, ml, aw_out, ctx, wo_bf, b_out, ao);
    ln_kernel<<<4096, 256, 0, stream>>>(x, ao, ln_w, ln_b, y_out);
}

// Round 10
// 192.792 us; speedup vs baseline: 1.0710x; 1.0710x over previous
//
#include <hip/hip_runtime.h>
#include <cstdint>

typedef __bf16 bf16;
typedef __bf16 bf16x8 __attribute__((ext_vector_type(8)));
typedef __bf16 bf16x4 __attribute__((ext_vector_type(4)));
typedef float  f32x4  __attribute__((ext_vector_type(4)));

#define MFMA_BF16(a, b, c) __builtin_amdgcn_mfma_f32_16x16x32_bf16(a, b, c, 0, 0, 0)

#define WAITCNT_VM(n) asm volatile("s_waitcnt vmcnt(" #n ")" ::: "memory")
#define CFENCE()      asm volatile("" ::: "memory")

// async global->LDS, 16B/lane; LDS dest affine in lane (base + lane*16).
__device__ __forceinline__ void async_load16(const void* g, void* l) {
    __builtin_amdgcn_global_load_lds(
        (__attribute__((address_space(1))) uint32_t*)(uintptr_t)g,
        (__attribute__((address_space(3))) uint32_t*)(uint32_t)(uintptr_t)l,
        16, 0, 0);
}

// ---------------- fused fp32 -> bf16 convert (x + w_qkv in one launch) ----------------
__global__ void cvt3_kernel(const float* __restrict__ s0, bf16* __restrict__ d0, int n0,
                            const float* __restrict__ s1, bf16* __restrict__ d1, int n1) {
    int i = blockIdx.x * blockDim.x + threadIdx.x;
    const float* s; bf16* d; int j = i;
    if (j < n0) { s = s0; d = d0; }
    else { j -= n0; if (j >= n1) return; s = s1; d = d1; }
    float4 v = ((const float4*)s)[j];
    bf16x4 o;
    o[0] = (bf16)v.x; o[1] = (bf16)v.y; o[2] = (bf16)v.z; o[3] = (bf16)v.w;
    ((bf16x4*)d)[j] = o;
}

// ---------------- QKV GEMM: R7 schedule + L2-resident-B XCD mapping ----------------
// R9 post-mortem: qkv is cache-BW bound (384MB logical operand reads; per-XCD B working
// set was 6MB > 4MB L2 -> B re-streamed from L3 ~4x = ~190MB L3 traffic; invariant to
// all 6 loop schedules tried). R10 mapping: each XCD owns 3 B-panels (768KB, L2-resident
// for the whole kernel); A panels stream once, shared by 3 consecutive blocks.
__global__ __launch_bounds__(256) void gemm_qkv_kernel(
    const bf16* __restrict__ A, const bf16* __restrict__ W,
    const float* __restrict__ bias,
    bf16* __restrict__ Qb, bf16* __restrict__ Kb, bf16* __restrict__ Vt)
{
    const int Kd = 1024;
    __shared__ __attribute__((aligned(16))) bf16 smem[6 * 128 * 32];   // 48KB: sA[3] | sB[3]
    bf16* const sA0 = smem;
    bf16* const sB0 = smem + 3 * 4096;
    int tid = threadIdx.x, lane = tid & 63, wid = tid >> 6;
    int flat = blockIdx.y * 24 + blockIdx.x;          // 0..767
    int xcd = flat & 7, local = flat >> 3;            // 96 blocks per XCD
    int n0 = (xcd * 3 + local % 3) * 128;             // 3 B-panels/XCD = 768KB -> L2-resident
    int m0 = (local / 3) * 128;                       // A panels stream; 3 blocks share each
    int srow = wid * 32 + (lane >> 2);
    int pchunk = lane & 3;                       // physical chunk (LDS dest, linear)
    int jchunk = pchunk ^ ((lane >> 3) & 3);     // logical chunk (source); key=(srow>>1)&3
    const bf16* Ag = A + (size_t)(m0 + srow) * Kd + jchunk * 8;
    const bf16* Wg = W + (size_t)(n0 + srow) * Kd + jchunk * 8;
    int soff = srow * 32 + pchunk * 8;
    int wm = (wid & 1) * 64, wn = (wid >> 1) * 64;
    int lcol = lane & 15, quad = lane >> 4;
    int ckey = (lcol >> 1) & 3;                  // read-side swizzle key
    f32x4 acc[4][4] = {};
#define STG_Q(buf, k0_) do { \
        async_load16(Ag + (k0_), sA0 + (buf) * 4096 + soff); \
        async_load16(Ag + (k0_) + 16 * Kd, sA0 + (buf) * 4096 + soff + 512); \
        async_load16(Wg + (k0_), sB0 + (buf) * 4096 + soff); \
        async_load16(Wg + (k0_) + 16 * Kd, sB0 + (buf) * 4096 + soff + 512); \
    } while (0)
    STG_Q(0, 0);
    STG_Q(1, 32);
    STG_Q(2, 64);
    int cur = 0;
    for (int it = 0; it < 32; ++it) {
        if (it < 30)      { WAITCNT_VM(8); }
        else if (it == 30){ WAITCNT_VM(4); }
        else              { WAITCNT_VM(0); }
        __builtin_amdgcn_s_barrier();   // buf[cur] staged by ALL waves
        CFENCE();
        const bf16* cA = sA0 + cur * 4096;
        const bf16* cB = sB0 + cur * 4096;
        bf16x8 af[4], bfr[4];
#pragma unroll
        for (int i = 0; i < 4; i++)
            af[i] = *(const bf16x8*)&cA[(wm + i * 16 + lcol) * 32 + (quad ^ ckey) * 8];
#pragma unroll
        for (int i = 0; i < 4; i++)
            bfr[i] = *(const bf16x8*)&cB[(wn + i * 16 + lcol) * 32 + (quad ^ ckey) * 8];
#pragma unroll
        for (int i = 0; i < 4; i++)
#pragma unroll
            for (int j = 0; j < 4; j++)
                acc[i][j] = MFMA_BF16(af[i], bfr[j], acc[i][j]);
        CFENCE();
        __builtin_amdgcn_s_barrier();   // all waves done reading buf[cur]
        if (it + 3 < 32) STG_Q(cur, (it + 3) * 32);   // refill the buffer just consumed
        cur = (cur == 2) ? 0 : cur + 1;
    }
#undef STG_Q
    // ---- coalesced epilogue (LDS restage) ----
    const int LP = 136;                    // padded bf16 row stride (272B)
    bf16* sE = smem;                       // 128*136*2B = 34KB <= 48KB
    int part = n0 >> 10;                   // whole block is one of Q/K/V
    int h0 = (n0 & 1023) >> 6;
    int b = m0 >> 10, s0 = m0 & 1023;
    if (part == 2) {
#pragma unroll
        for (int j = 0; j < 4; j++) {
            float bv = bias[n0 + wn + j * 16 + lcol];
#pragma unroll
            for (int i = 0; i < 4; i++)
#pragma unroll
                for (int r = 0; r < 4; r++)
                    sE[(wn + j * 16 + lcol) * LP + (wm + i * 16 + quad * 4 + r)] = (bf16)(acc[i][j][r] + bv);
        }
        __syncthreads();
#pragma unroll
        for (int p = 0; p < 8; p++) {
            int c = p * 256 + tid;
            int nl = c >> 4, mc = (c & 15) * 8;
            int dd = nl & 63, h = h0 + (nl >> 6);
            *(bf16x8*)&Vt[(size_t)((b * 16 + h) * 64 + dd) * 1024 + s0 + mc] = *(const bf16x8*)&sE[nl * LP + mc];
        }
    } else {
        float scv = (part == 0) ? 0.125f : 1.0f;
        bf16* dst = (part == 0) ? Qb : Kb;
#pragma unroll
        for (int j = 0; j < 4; j++) {
            float bv = bias[n0 + wn + j * 16 + lcol];
#pragma unroll
            for (int i = 0; i < 4; i++)
#pragma unroll
                for (int r = 0; r < 4; r++)
                    sE[(wm + i * 16 + quad * 4 + r) * LP + (wn + j * 16 + lcol)] = (bf16)((acc[i][j][r] + bv) * scv);
        }
        __syncthreads();
#pragma unroll
        for (int p = 0; p < 8; p++) {
            int c = p * 256 + tid;
            int half = c >> 10, idx = c & 1023;
            int m = idx >> 3, nc = (idx & 7) * 8;
            *(bf16x8*)&dst[(size_t)((b * 16 + h0 + half) * 1024 + s0 + m) * 64 + nc] =
                *(const bf16x8*)&sE[m * LP + half * 64 + nc];
        }
    }
}

// ---------------- flash attention (+ piggybacked w_out cvt): 8-wave blocks ----------------
__global__ __launch_bounds__(512) void flash_kernel(
    const bf16* __restrict__ Qb, const bf16* __restrict__ Kb, const bf16* __restrict__ Vt,
    bf16* __restrict__ ctx, float* __restrict__ ml,
    const float* __restrict__ wof, bf16* __restrict__ wob)
{
    __shared__ bf16 sK[2][64 * 64];     // [buf][key][d], chunk-swizzled
    __shared__ bf16 sV[2][64 * 64];     // [buf][d][key], chunk-swizzled
    __shared__ bf16 pt[8][16 * 64];     // per-wave 16q x 64k transpose tile, XOR-swizzled
    int tid = threadIdx.x, lane = tid & 63, wid = tid >> 6;
    int bx = blockIdx.x;
    if (bx >= 512) {
        int i = (bx - 512) * 512 + tid;          // [0, 262144)
        float4 v = ((const float4*)wof)[i];
        bf16x4 o;
        o[0] = (bf16)v.x; o[1] = (bf16)v.y; o[2] = (bf16)v.z; o[3] = (bf16)v.w;
        ((bf16x4*)wob)[i] = o;
        return;
    }
    int orig = (bx & 7) * 64 + (bx >> 3);   // XCD-contiguous remap (bijective over 512)
    int qt = orig & 7;
    int h = (orig >> 3) & 15;
    int b = orig >> 7;
    int lcol = lane & 15, quad = lane >> 4;
    size_t base = (size_t)(b * 16 + h) * 65536;

    int q0 = qt * 128 + wid * 16;
    const bf16* qp = Qb + base + (size_t)(q0 + lcol) * 64 + quad * 8;
    bf16x8 a0 = *(const bf16x8*)qp;
    bf16x8 a1 = *(const bf16x8*)(qp + 32);

    char* wpt = (char*)&pt[wid][0];
    int sr = tid >> 3;                   // staged row 0..63
    int pp = tid & 7;                    // physical chunk
    int jj = pp ^ (sr & 7);              // logical chunk (swizzle key = row & 7)
    int sw = lcol & 7;                   // read-side swizzle key

#define STAGE_KV(buf, kt_) do { \
        async_load16(Kb + base + (size_t)((kt_) * 64 + sr) * 64 + jj * 8, &sK[buf][sr * 64 + pp * 8]); \
        async_load16(Vt + base + (size_t)sr * 1024 + (kt_) * 64 + jj * 8, &sV[buf][sr * 64 + pp * 8]); \
    } while (0)

    float l_[4] = {0.f, 0.f, 0.f, 0.f};
    f32x4 o[4] = {};

    STAGE_KV(0, 0);
    int cur = 0;
    for (int kt = 0; kt < 16; kt++) {
        __syncthreads();
        if (kt < 15) STAGE_KV(cur ^ 1, kt + 1);
        const bf16* sKc = &sK[cur][0];
        const bf16* sVc = &sV[cur][0];
#pragma unroll
        for (int nt = 0; nt < 4; nt++) {
            int ck = quad ^ sw;
            bf16x8 bk0 = *(const bf16x8*)&sKc[(nt * 16 + lcol) * 64 + ck * 8];
            bf16x8 bk1 = *(const bf16x8*)&sKc[(nt * 16 + lcol) * 64 + (ck ^ 4) * 8];
            f32x4 s = {};
            s = MFMA_BF16(a0, bk0, s);
            s = MFMA_BF16(a1, bk1, s);
#pragma unroll
            for (int rr = 0; rr < 4; rr++) {
                float p = __expf(s[rr]);
                l_[rr] += p;
                int row = quad * 4 + rr;
                *(bf16*)(wpt + row * 128 + ((nt * 32 + lcol * 2) ^ ((row & 7) << 4))) = (bf16)p;
            }
        }
#pragma unroll
        for (int kf = 0; kf < 2; kf++) {
            bf16x8 pa = *(const bf16x8*)(wpt + lcol * 128 + (((kf * 4 + quad) ^ sw) << 4));
#pragma unroll
            for (int dt = 0; dt < 4; dt++) {
                bf16x8 vb = *(const bf16x8*)&sVc[(dt * 16 + lcol) * 64 + ((kf * 4 + quad) ^ sw) * 8];
                o[dt] = MFMA_BF16(pa, vb, o[dt]);
            }
        }
        cur ^= 1;
    }
#undef STAGE_KV
#pragma unroll
    for (int mk = 1; mk < 16; mk <<= 1)
#pragma unroll
        for (int rr = 0; rr < 4; rr++) l_[rr] += __shfl_xor(l_[rr], mk, 64);
    // stage o -> pt (wave-private, swizzled), then coalesced 16B stores
#pragma unroll
    for (int rr = 0; rr < 4; rr++) {
        float inv = 1.f / l_[rr];
        int row = quad * 4 + rr;
#pragma unroll
        for (int dt = 0; dt < 4; dt++)
            *(bf16*)(wpt + row * 128 + ((dt * 32 + lcol * 2) ^ ((row & 7) << 4))) = (bf16)(o[dt][rr] * inv);
        if (lcol == 0)
            ml[(size_t)(b * 16 + h) * 1024 + q0 + row] = l_[rr];
    }
    int r8a = lane >> 3, ca = lane & 7;
#pragma unroll
    for (int half = 0; half < 2; half++) {
        int r8 = r8a + half * 8;
        bf16x8 v = *(const bf16x8*)(wpt + r8 * 128 + ((ca * 16) ^ ((r8 & 7) << 4)));
        *(bf16x8*)&ctx[(size_t)(b * 1024 + q0 + r8) * 1024 + h * 64 + ca * 8] = v;
    }
}

// ---------------- MERGED aw + out-proj GEMM (independent ops, one launch = overlap) ----------------
// Blocks 0..511: aw (8-wave, reg-pipelined Q/ml). Blocks 512..767: out-proj 128x128-tile
// GEMM (8-wave, 3-deep 2-barrier counted-vmcnt schedule). ao -> y_out scratch.
__global__ __launch_bounds__(512) void awo_kernel(
    const bf16* __restrict__ Qb, const bf16* __restrict__ Kb,
    const float* __restrict__ ml, float* __restrict__ aw,
    const bf16* __restrict__ ctx, const bf16* __restrict__ wob,
    const float* __restrict__ bias, float* __restrict__ yao)
{
    __shared__ __attribute__((aligned(16))) bf16 smem[6 * 128 * 32];   // 48KB union
    int tid = threadIdx.x, lane = tid & 63, wid = tid >> 6;
    int bx = blockIdx.x;
    int lcol = lane & 15, quad = lane >> 4;

    if (bx >= 512) {
        // ---- out-proj GEMM: 128x128 tile, 512 threads, 3-deep 2-barrier counted vmcnt ----
        const int Kd = 1024;
        bf16* const sA0 = smem;
        bf16* const sB0 = smem + 3 * 4096;
        int obx = bx - 512;                       // 0..255
        int m0 = (obx >> 3) * 128, n0 = (obx & 7) * 128;
        int srow = tid >> 2;                      // 0..127 (one 128x32 tile per stage)
        int pchunk = tid & 3;
        int jchunk = pchunk ^ ((tid >> 3) & 3);   // key=(srow>>1)&3
        const bf16* Ag = ctx + (size_t)(m0 + srow) * Kd + jchunk * 8;
        const bf16* Wg = wob + (size_t)(n0 + srow) * Kd + jchunk * 8;
        int soff = srow * 32 + pchunk * 8;
        int wm = (wid & 3) * 32, wn = (wid >> 2) * 64;
        int ckey = (lcol >> 1) & 3;
        f32x4 acc[2][4] = {};
#define STG_O(buf, k0_) do { \
        async_load16(Ag + (k0_), sA0 + (buf) * 4096 + soff); \
        async_load16(Wg + (k0_), sB0 + (buf) * 4096 + soff); \
    } while (0)
        STG_O(0, 0);
        STG_O(1, 32);
        STG_O(2, 64);
        int cur = 0;
        for (int it = 0; it < 32; ++it) {
            if (it < 30)      { WAITCNT_VM(4); }
            else if (it == 30){ WAITCNT_VM(2); }
            else              { WAITCNT_VM(0); }
            __builtin_amdgcn_s_barrier();
            CFENCE();
            const bf16* cA = sA0 + cur * 4096;
            const bf16* cB = sB0 + cur * 4096;
            bf16x8 af[2], bfr[4];
#pragma unroll
            for (int i = 0; i < 2; i++)
                af[i] = *(const bf16x8*)&cA[(wm + i * 16 + lcol) * 32 + (quad ^ ckey) * 8];
#pragma unroll
            for (int j = 0; j < 4; j++)
                bfr[j] = *(const bf16x8*)&cB[(wn + j * 16 + lcol) * 32 + (quad ^ ckey) * 8];
#pragma unroll
            for (int i = 0; i < 2; i++)
#pragma unroll
                for (int j = 0; j < 4; j++)
                    acc[i][j] = MFMA_BF16(af[i], bfr[j], acc[i][j]);
            CFENCE();
            __builtin_amdgcn_s_barrier();
            if (it + 3 < 32) STG_O(cur, (it + 3) * 32);
            cur = (cur == 2) ? 0 : cur + 1;
        }
#undef STG_O
#pragma unroll
        for (int j = 0; j < 4; j++) {
            int n = n0 + wn + j * 16 + lcol;
            float bv = bias[n];
#pragma unroll
            for (int i = 0; i < 2; i++) {
                int m = m0 + wm + i * 16 + quad * 4;
#pragma unroll
                for (int r = 0; r < 4; r++) yao[(size_t)(m + r) * 1024 + n] = acc[i][j][r] + bv;
            }
        }
        return;
    }

    // ---- aw: 8-wave, dbuf K staging, reg-pipelined Q/ml ----
    bf16* const sK0 = smem;                       // 2 x 4096 elements
    int orig = (bx & 7) * 64 + (bx >> 3);         // bijective over 512
    int kt = orig & 15;
    int qt = (orig >> 4) & 7;
    int b = orig >> 7;
    int q0 = qt * 128 + wid * 16;
    int kbase = kt * 64;
    int sw = lcol & 7;
    int sr = tid >> 3, pp = tid & 7, jj = pp ^ (sr & 7);   // 1 chunk per thread (8KB)

#define STAGE_K(buf, hh) \
        async_load16(Kb + (size_t)(b * 16 + (hh)) * 65536 + (size_t)(kbase + sr) * 64 + jj * 8, \
                     sK0 + (buf) * 4096 + sr * 64 + pp * 8)

    float acc[16];
#pragma unroll
    for (int i = 0; i < 16; i++) acc[i] = 0.f;

    bf16x8 a0c, a1c, a0n, a1n;
    float4 mvC, mvN;
    {
        const bf16* qp = Qb + (size_t)(b * 16) * 65536 + (size_t)(q0 + lcol) * 64 + quad * 8;
        a0c = *(const bf16x8*)qp;
        a1c = *(const bf16x8*)(qp + 32);
        mvC = *(const float4*)(ml + (size_t)(b * 16) * 1024 + q0 + quad * 4);
    }
    STAGE_K(0, 0);
    int cur = 0;
    for (int h = 0; h < 16; h++) {
        __syncthreads();
        if (h < 15) {
            STAGE_K(cur ^ 1, h + 1);
            const bf16* qp = Qb + (size_t)(b * 16 + h + 1) * 65536 + (size_t)(q0 + lcol) * 64 + quad * 8;
            a0n = *(const bf16x8*)qp;
            a1n = *(const bf16x8*)(qp + 32);
            mvN = *(const float4*)(ml + (size_t)(b * 16 + h + 1) * 1024 + q0 + quad * 4);
        }
        float scale[4] = {0.0625f / mvC.x, 0.0625f / mvC.y, 0.0625f / mvC.z, 0.0625f / mvC.w};
        const bf16* sKc = sK0 + cur * 4096;
#pragma unroll
        for (int nt = 0; nt < 4; nt++) {
            int ck = quad ^ sw;
            bf16x8 bk0 = *(const bf16x8*)&sKc[(nt * 16 + lcol) * 64 + ck * 8];
            bf16x8 bk1 = *(const bf16x8*)&sKc[(nt * 16 + lcol) * 64 + (ck ^ 4) * 8];
            f32x4 s = {};
            s = MFMA_BF16(a0c, bk0, s);
            s = MFMA_BF16(a1c, bk1, s);
#pragma unroll
            for (int rr = 0; rr < 4; rr++)
                acc[nt * 4 + rr] += __expf(s[rr]) * scale[rr];
        }
        if (h < 15) { a0c = a0n; a1c = a1n; mvC = mvN; }
        cur ^= 1;
    }
#undef STAGE_K
#pragma unroll
    for (int nt = 0; nt < 4; nt++)
#pragma unroll
        for (int rr = 0; rr < 4; rr++)
            aw[(size_t)(b * 1024 + q0 + quad * 4 + rr) * 1024 + kbase + nt * 16 + lcol] = acc[nt * 4 + rr];
}

// ---------------- residual + LayerNorm (in-place over yao = y_out) ----------------
__global__ __launch_bounds__(256) void ln_kernel(
    const float* __restrict__ x, const float* __restrict__ ao,
    const float* __restrict__ w, const float* __restrict__ bsh,
    float* __restrict__ y)
{
    int row = blockIdx.x, tid = threadIdx.x;
    float4 xv = ((const float4*)(x + (size_t)row * 1024))[tid];
    float4 av = ((const float4*)(ao + (size_t)row * 1024))[tid];
    float4 v = {xv.x + av.x, xv.y + av.y, xv.z + av.z, xv.w + av.w};
    float s = v.x + v.y + v.z + v.w;
    float ss = v.x * v.x + v.y * v.y + v.z * v.z + v.w * v.w;
#pragma unroll
    for (int off = 32; off; off >>= 1) { s += __shfl_down(s, off); ss += __shfl_down(ss, off); }
    __shared__ float rs[4], rss[4];
    int lane = tid & 63, wid = tid >> 6;
    if (lane == 0) { rs[wid] = s; rss[wid] = ss; }
    __syncthreads();
    s = rs[0] + rs[1] + rs[2] + rs[3];
    ss = rss[0] + rss[1] + rss[2] + rss[3];
    float mean = s * (1.f / 1024.f);
    float var = ss * (1.f / 1024.f) - mean * mean;
    float inv = rsqrtf(var + 1e-5f);
    float4 wv = ((const float4*)w)[tid];
    float4 bv = ((const float4*)bsh)[tid];
    float4 o;
    o.x = (v.x - mean) * inv * wv.x + bv.x;
    o.y = (v.y - mean) * inv * wv.y + bv.y;
    o.z = (v.z - mean) * inv * wv.z + bv.z;
    o.w = (v.w - mean) * inv * wv.w + bv.w;
    ((float4*)y)[row * 256 + tid] = o;
}

extern "C" void kernel_launch(void* const* d_in, const int* in_sizes, int n_in,
                              void* d_out, int out_size, void* d_ws, size_t ws_size,
                              hipStream_t stream) {
    const float* x     = (const float*)d_in[0];
    const float* w_qkv = (const float*)d_in[1];
    const float* b_qkv = (const float*)d_in[2];
    const float* w_out = (const float*)d_in[3];
    const float* b_out = (const float*)d_in[4];
    const float* ln_w  = (const float*)d_in[5];
    const float* ln_b  = (const float*)d_in[6];

    char* ws = (char*)d_ws;
    // [0,8M) Qb | [8,16M) Kb | [16,24M) Vt | [24,32M) ctx | [32,32.25M) ml |
    // x_bf [33,41M), wq_bf [41,47M) live only until gemm_qkv;
    // wo_bf [33,35M) after qkv (x_bf dead; written by flash-launch cvt riders);
    // ao lives in y_out (d_out scratch; ln runs in-place).
    bf16*   Qb    = (bf16*)(ws);
    bf16*   Kb    = (bf16*)(ws + (8ull  << 20));
    bf16*   Vt    = (bf16*)(ws + (16ull << 20));
    bf16*   ctx   = (bf16*)(ws + (24ull << 20));
    float*  ml    = (float*)(ws + (32ull << 20));
    bf16*   x_bf  = (bf16*)(ws + (33ull << 20));
    bf16*   wq_bf = (bf16*)(ws + (41ull << 20));
    bf16*   wo_bf = (bf16*)(ws + (33ull << 20));

    float* y_out  = (float*)d_out;
    float* aw_out = y_out + 4ull * 1024 * 1024;
    float* ao     = y_out;                      // scratch; ln in-place

    cvt3_kernel<<<7168, 256, 0, stream>>>(x, x_bf, 1048576, w_qkv, wq_bf, 786432);
    gemm_qkv_kernel<<<dim3(24, 32), 256, 0, stream>>>(x_bf, wq_bf, b_qkv, Qb, Kb, Vt);
    flash_kernel<<<1024, 512, 0, stream>>>(Qb, Kb, Vt, ctx, ml, w_out, wo_bf);
    awo_kernel<<<768, 512, 0, stream>>>(Qb, Kb, ml, aw_out, ctx, wo_bf, b_out, ao);
    ln_kernel<<<4096, 256, 0, stream>>>(x, ao, ln_w, ln_b, y_out);
}